// Round 4
// baseline (143.103 us; speedup 1.0000x reference)
//
#include <hip/hip_runtime.h>

#define COORD 5.0f
#define NO_OBJ 0.5f
#define NCELLS (8192 * 49)
#define INV_B (1.0f / 8192.0f)

#define CPB 128                      // threads per block = cells per tile
#define FPT (CPB * 30)               // floats per tile per array = 3840
#define NBLK (NCELLS / (CPB * 2))    // 1568 blocks, two tiles per block

__device__ __forceinline__ float iou_calc(float ax1, float ay1, float ax2, float ay2,
                                          float bx1, float by1, float bx2, float by2) {
    float iw = fminf(ax2, bx2) - fmaxf(ax1, bx1);
    iw = fmaxf(iw, 0.0f);
    float ih = fminf(ay2, by2) - fmaxf(ay1, by1);
    ih = fmaxf(ih, 0.0f);
    float inter = iw * ih;
    float area_a = (ax2 - ax1) * (ay2 - ay1);
    float area_b = (bx2 - bx1) * (by2 - by1);
    float uni = area_a + area_b - inter;
    return uni > 0.0f ? inter / uni : 0.0f;
}

// Per-cell loss computed from LDS-staged tiles. tid*30 floats is 8B-aligned.
__device__ __forceinline__ float cell_loss(const float* __restrict__ sd,
                                           const float* __restrict__ sl,
                                           int idx, int tid) {
    const int cell = idx % 49;
    const float r = (float)(cell / 7);
    const float c = (float)(cell % 7);

    float d[30], l[30];
    const float2* dp = (const float2*)(sd + tid * 30);
    const float2* lp = (const float2*)(sl + tid * 30);
#pragma unroll
    for (int i = 0; i < 15; i++) {
        float2 v = dp[i];
        d[2 * i] = v.x; d[2 * i + 1] = v.y;
        float2 w2 = lp[i];
        l[2 * i] = w2.x; l[2 * i + 1] = w2.y;
    }

    const float inv_g = 1.0f / 7.0f;
    float cx1 = (d[0] + c) * inv_g, cy1 = (d[1] + r) * inv_g;
    float b1x1 = cx1 - d[2] * 0.5f, b1y1 = cy1 - d[3] * 0.5f;
    float b1x2 = cx1 + d[2] * 0.5f, b1y2 = cy1 + d[3] * 0.5f;
    float cx2 = (d[5] + c) * inv_g, cy2 = (d[6] + r) * inv_g;
    float b2x1 = cx2 - d[7] * 0.5f, b2y1 = cy2 - d[8] * 0.5f;
    float b2x2 = cx2 + d[7] * 0.5f, b2y2 = cy2 + d[8] * 0.5f;
    float gx = (l[0] + c) * inv_g, gy = (l[1] + r) * inv_g;
    float gx1 = gx - l[2] * 0.5f, gy1 = gy - l[3] * 0.5f;
    float gx2 = gx + l[2] * 0.5f, gy2 = gy + l[3] * 0.5f;

    float iou1 = iou_calc(b1x1, b1y1, b1x2, b1y2, gx1, gy1, gx2, gy2);
    float iou2 = iou_calc(b2x1, b2y1, b2x2, b2y2, gx1, gy1, gx2, gy2);
    bool resp1 = iou1 >= iou2;

    float xy1 = (d[0] - l[0]) * (d[0] - l[0]) + (d[1] - l[1]) * (d[1] - l[1]);
    float xy2 = (d[5] - l[5]) * (d[5] - l[5]) + (d[6] - l[6]) * (d[6] - l[6]);
    float s2 = sqrtf(d[2]) - sqrtf(l[2]);
    float s3 = sqrtf(d[3]) - sqrtf(l[3]);
    float wh1 = s2 * s2 + s3 * s3;
    float s7 = sqrtf(d[7]) - sqrtf(l[7]);
    float s8 = sqrtf(d[8]) - sqrtf(l[8]);
    float wh2 = s7 * s7 + s8 * s8;

    float d4 = d[4], d9 = d[9];
    float co = COORD * (resp1 ? xy1 : xy2);
    float wh = COORD * (resp1 ? wh1 : wh2);
    float ci = resp1 ? (d4 - iou1) * (d4 - iou1) : (d9 - iou2) * (d9 - iou2);
    float noobj_in = NO_OBJ * (resp1 ? d9 * d9 : d4 * d4);
    float cls = 0.0f;
#pragma unroll
    for (int i = 10; i < 30; i++) {
        float t = d[i] - l[i];
        cls += t * t;
    }

    return (l[4] == 1.0f) ? (co + wh + ci + noobj_in + cls)
                          : NO_OBJ * (d4 * d4 + d9 * d9);
}

// Two tiles per block with register-prefetch double buffering (T14 split):
// tile1's 16 wave-wide global loads are issued BEFORE tile0's compute, so
// ~16 KB/block of HBM reads stay in flight under the LDS-gather + VALU phase.
// Single 30.7 KB LDS buffer keeps 5 blocks/CU residency.
__global__ __launch_bounds__(CPB) void yolo_loss_kernel(
    const float* __restrict__ data, const float* __restrict__ labels,
    float* __restrict__ ws) {
    __shared__ float sd[FPT];
    __shared__ float sl[FPT];

    const int tid = threadIdx.x;
    const size_t base0 = (size_t)blockIdx.x * (2 * FPT);

    float4* sd4 = (float4*)sd;
    float4* sl4 = (float4*)sl;

    float4 pd[7], pl[7];
    float2 pd2, pl2;

    // ---- load tile0 -> regs (coalesced: 960 float4/array = 7 rounds + tail)
    {
        const float4* gd4 = (const float4*)(data + base0);
        const float4* gl4 = (const float4*)(labels + base0);
#pragma unroll
        for (int j = 0; j < 7; j++) {
            pd[j] = gd4[j * 128 + tid];
            pl[j] = gl4[j * 128 + tid];
        }
        pd2 = ((const float2*)(data + base0 + 3584))[tid];
        pl2 = ((const float2*)(labels + base0 + 3584))[tid];
    }
    // ---- write tile0 -> LDS
#pragma unroll
    for (int j = 0; j < 7; j++) {
        sd4[j * 128 + tid] = pd[j];
        sl4[j * 128 + tid] = pl[j];
    }
    ((float2*)(sd + 3584))[tid] = pd2;
    ((float2*)(sl + 3584))[tid] = pl2;
    __syncthreads();

    // ---- issue tile1 loads -> regs (in flight during tile0 compute)
    {
        const float4* gd4 = (const float4*)(data + base0 + FPT);
        const float4* gl4 = (const float4*)(labels + base0 + FPT);
#pragma unroll
        for (int j = 0; j < 7; j++) {
            pd[j] = gd4[j * 128 + tid];
            pl[j] = gl4[j * 128 + tid];
        }
        pd2 = ((const float2*)(data + base0 + FPT + 3584))[tid];
        pl2 = ((const float2*)(labels + base0 + FPT + 3584))[tid];
    }

    // ---- compute tile0
    const int idx0 = blockIdx.x * (2 * CPB) + tid;
    float acc = cell_loss(sd, sl, idx0, tid);

    __syncthreads();  // all waves done reading tile0 LDS

    // ---- write tile1 -> LDS (compiler waits vmcnt here, after the compute)
#pragma unroll
    for (int j = 0; j < 7; j++) {
        sd4[j * 128 + tid] = pd[j];
        sl4[j * 128 + tid] = pl[j];
    }
    ((float2*)(sd + 3584))[tid] = pd2;
    ((float2*)(sl + 3584))[tid] = pl2;
    __syncthreads();

    // ---- compute tile1
    acc += cell_loss(sd, sl, idx0 + CPB, tid);
    acc *= INV_B;

    // wave reduction -> per-block partial
#pragma unroll
    for (int off = 32; off > 0; off >>= 1)
        acc += __shfl_down(acc, off, 64);

    __shared__ float wsum[2];
    if ((tid & 63) == 0) wsum[tid >> 6] = acc;
    __syncthreads();
    if (tid == 0) ws[blockIdx.x] = wsum[0] + wsum[1];
}

__global__ __launch_bounds__(256) void reduce_kernel(const float* __restrict__ ws,
                                                     float* __restrict__ out) {
    float s = 0.0f;
    for (int i = threadIdx.x; i < NBLK; i += 256) s += ws[i];
#pragma unroll
    for (int off = 32; off > 0; off >>= 1)
        s += __shfl_down(s, off, 64);
    __shared__ float w[4];
    if ((threadIdx.x & 63) == 0) w[threadIdx.x >> 6] = s;
    __syncthreads();
    if (threadIdx.x == 0) out[0] = w[0] + w[1] + w[2] + w[3];
}

extern "C" void kernel_launch(void* const* d_in, const int* in_sizes, int n_in,
                              void* d_out, int out_size, void* d_ws, size_t ws_size,
                              hipStream_t stream) {
    const float* data = (const float*)d_in[0];
    const float* labels = (const float*)d_in[1];
    float* out = (float*)d_out;
    float* ws = (float*)d_ws;  // NBLK floats of scratch

    yolo_loss_kernel<<<NBLK, CPB, 0, stream>>>(data, labels, ws);
    reduce_kernel<<<1, 256, 0, stream>>>(ws, out);
}

// Round 5
// 114.440 us; speedup vs baseline: 1.2505x; 1.2505x over previous
//
#include <hip/hip_runtime.h>

#define COORD 5.0f
#define NO_OBJ 0.5f
#define NCELLS (8192 * 49)
#define INV_B (1.0f / 8192.0f)

#define CPB 128                      // threads per block = cells per tile
#define FPT (CPB * 30)               // floats per tile per array = 3840 (15360 B)
#define NTILES (NCELLS / CPB)        // 3136 tiles
#define NPBLK 512                    // persistent blocks: 2/CU, each does 6-7 tiles

__device__ __forceinline__ float iou_calc(float ax1, float ay1, float ax2, float ay2,
                                          float bx1, float by1, float bx2, float by2) {
    float iw = fminf(ax2, bx2) - fmaxf(ax1, bx1);
    iw = fmaxf(iw, 0.0f);
    float ih = fminf(ay2, by2) - fmaxf(ay1, by1);
    ih = fmaxf(ih, 0.0f);
    float inter = iw * ih;
    float area_a = (ax2 - ax1) * (ay2 - ay1);
    float area_b = (bx2 - bx1) * (by2 - by1);
    float uni = area_a + area_b - inter;
    return uni > 0.0f ? inter / uni : 0.0f;
}

// Async global->LDS staging of one 15360 B tile: 7 rounds x 16 B/lane + 2 x 4 B/lane
// = 120 B/lane. Zero VGPR payload (no spill risk); LDS dest is linear lane*size.
__device__ __forceinline__ void stage_tile(const float* __restrict__ g, float* s, int tid) {
#pragma unroll
    for (int j = 0; j < 7; j++) {
        __builtin_amdgcn_global_load_lds(
            (const __attribute__((address_space(1))) void*)(g + j * 512 + tid * 4),
            (__attribute__((address_space(3))) void*)(s + j * 512 + tid * 4), 16, 0, 0);
    }
#pragma unroll
    for (int j = 0; j < 2; j++) {
        __builtin_amdgcn_global_load_lds(
            (const __attribute__((address_space(1))) void*)(g + 3584 + j * 128 + tid),
            (__attribute__((address_space(3))) void*)(s + 3584 + j * 128 + tid), 4, 0, 0);
    }
}

// Per-cell loss from LDS-staged tiles (stride-30 gather, 4-way bank conflict: cheap).
__device__ __forceinline__ float cell_loss(const float* __restrict__ sd,
                                           const float* __restrict__ sl,
                                           int idx, int tid) {
    const int cell = idx % 49;
    const float r = (float)(cell / 7);
    const float c = (float)(cell % 7);

    float d[30], l[30];
    const float2* dp = (const float2*)(sd + tid * 30);
    const float2* lp = (const float2*)(sl + tid * 30);
#pragma unroll
    for (int i = 0; i < 15; i++) {
        float2 v = dp[i];
        d[2 * i] = v.x; d[2 * i + 1] = v.y;
        float2 w2 = lp[i];
        l[2 * i] = w2.x; l[2 * i + 1] = w2.y;
    }

    const float inv_g = 1.0f / 7.0f;
    float cx1 = (d[0] + c) * inv_g, cy1 = (d[1] + r) * inv_g;
    float b1x1 = cx1 - d[2] * 0.5f, b1y1 = cy1 - d[3] * 0.5f;
    float b1x2 = cx1 + d[2] * 0.5f, b1y2 = cy1 + d[3] * 0.5f;
    float cx2 = (d[5] + c) * inv_g, cy2 = (d[6] + r) * inv_g;
    float b2x1 = cx2 - d[7] * 0.5f, b2y1 = cy2 - d[8] * 0.5f;
    float b2x2 = cx2 + d[7] * 0.5f, b2y2 = cy2 + d[8] * 0.5f;
    float gx = (l[0] + c) * inv_g, gy = (l[1] + r) * inv_g;
    float gx1 = gx - l[2] * 0.5f, gy1 = gy - l[3] * 0.5f;
    float gx2 = gx + l[2] * 0.5f, gy2 = gy + l[3] * 0.5f;

    float iou1 = iou_calc(b1x1, b1y1, b1x2, b1y2, gx1, gy1, gx2, gy2);
    float iou2 = iou_calc(b2x1, b2y1, b2x2, b2y2, gx1, gy1, gx2, gy2);
    bool resp1 = iou1 >= iou2;

    float xy1 = (d[0] - l[0]) * (d[0] - l[0]) + (d[1] - l[1]) * (d[1] - l[1]);
    float xy2 = (d[5] - l[5]) * (d[5] - l[5]) + (d[6] - l[6]) * (d[6] - l[6]);
    float s2 = sqrtf(d[2]) - sqrtf(l[2]);
    float s3 = sqrtf(d[3]) - sqrtf(l[3]);
    float wh1 = s2 * s2 + s3 * s3;
    float s7 = sqrtf(d[7]) - sqrtf(l[7]);
    float s8 = sqrtf(d[8]) - sqrtf(l[8]);
    float wh2 = s7 * s7 + s8 * s8;

    float d4 = d[4], d9 = d[9];
    float co = COORD * (resp1 ? xy1 : xy2);
    float wh = COORD * (resp1 ? wh1 : wh2);
    float ci = resp1 ? (d4 - iou1) * (d4 - iou1) : (d9 - iou2) * (d9 - iou2);
    float noobj_in = NO_OBJ * (resp1 ? d9 * d9 : d4 * d4);
    float cls = 0.0f;
#pragma unroll
    for (int i = 10; i < 30; i++) {
        float t = d[i] - l[i];
        cls += t * t;
    }

    return (l[4] == 1.0f) ? (co + wh + ci + noobj_in + cls)
                          : NO_OBJ * (d4 * d4 + d9 * d9);
}

// Persistent double-buffered pipeline: while computing tile i from buf[cur], the
// async global_load_lds for tile i+NPBLK fills buf[cur^1]. __syncthreads() at
// loop top drains vmcnt (loads had the whole compute phase to land -> short wait)
// and guards buffer reuse across waves.
__global__ __launch_bounds__(CPB) void yolo_loss_kernel(
    const float* __restrict__ data, const float* __restrict__ labels,
    float* __restrict__ ws) {
    __shared__ float sd[2][FPT];
    __shared__ float sl[2][FPT];

    const int tid = threadIdx.x;
    float acc = 0.0f;
    int cur = 0;

    // prologue: stage first tile
    stage_tile(data + (size_t)blockIdx.x * FPT, sd[0], tid);
    stage_tile(labels + (size_t)blockIdx.x * FPT, sl[0], tid);

    for (int i = blockIdx.x; i < NTILES; i += NPBLK) {
        __syncthreads();  // vmcnt drain: buf[cur] staged + all waves done with buf[cur^1]
        const int nxt = i + NPBLK;
        if (nxt < NTILES) {
            stage_tile(data + (size_t)nxt * FPT, sd[cur ^ 1], tid);
            stage_tile(labels + (size_t)nxt * FPT, sl[cur ^ 1], tid);
        }
        acc += cell_loss(sd[cur], sl[cur], i * CPB + tid, tid);
        cur ^= 1;
    }
    acc *= INV_B;

    // wave reduction -> per-block partial
#pragma unroll
    for (int off = 32; off > 0; off >>= 1)
        acc += __shfl_down(acc, off, 64);

    __syncthreads();  // reuse sd[0] base as the partial exchange
    if ((tid & 63) == 0) sd[0][tid >> 6] = acc;
    __syncthreads();
    if (tid == 0) ws[blockIdx.x] = sd[0][0] + sd[0][1];
}

__global__ __launch_bounds__(256) void reduce_kernel(const float* __restrict__ ws,
                                                     float* __restrict__ out) {
    float s = 0.0f;
    for (int i = threadIdx.x; i < NPBLK; i += 256) s += ws[i];
#pragma unroll
    for (int off = 32; off > 0; off >>= 1)
        s += __shfl_down(s, off, 64);
    __shared__ float w[4];
    if ((threadIdx.x & 63) == 0) w[threadIdx.x >> 6] = s;
    __syncthreads();
    if (threadIdx.x == 0) out[0] = w[0] + w[1] + w[2] + w[3];
}

extern "C" void kernel_launch(void* const* d_in, const int* in_sizes, int n_in,
                              void* d_out, int out_size, void* d_ws, size_t ws_size,
                              hipStream_t stream) {
    const float* data = (const float*)d_in[0];
    const float* labels = (const float*)d_in[1];
    float* out = (float*)d_out;
    float* ws = (float*)d_ws;  // NPBLK floats of scratch

    yolo_loss_kernel<<<NPBLK, CPB, 0, stream>>>(data, labels, ws);
    reduce_kernel<<<1, 256, 0, stream>>>(ws, out);
}